// Round 1
// baseline (1261.751 us; speedup 1.0000x reference)
//
#include <hip/hip_runtime.h>
#include <math.h>

#define Bn 128
#define Tn 512
#define Dn 32
#define Hn 128
#define Gn 512   // 4*H
#define Ln 3

// LDS-only barrier: does NOT drain vmcnt.
#define BAR_LDS() asm volatile("s_waitcnt lgkmcnt(0)\n\ts_barrier" ::: "memory")

typedef _Float16 h2 __attribute__((ext_vector_type(2)));
typedef _Float16 half8 __attribute__((ext_vector_type(8)));   // MFMA A/B frag
typedef float f32x4 __attribute__((ext_vector_type(4)));      // MFMA acc

__device__ __forceinline__ float dot2(h2 a, h2 b, float c) {
    return __builtin_amdgcn_fdot2(a, b, c, false);
}
__device__ __forceinline__ h2 pkh(float a, float b) {
    h2 r; r.x = (_Float16)a; r.y = (_Float16)b; return r;
}
__device__ __forceinline__ h2 bcast2(h2 v, int l) {
    int i = __builtin_amdgcn_readlane(__builtin_bit_cast(int, v), l);
    return __builtin_bit_cast(h2, i);
}
__device__ __forceinline__ float sigm(float x) {
    return __builtin_amdgcn_rcpf(1.f + __expf(-x));
}
__device__ __forceinline__ float tanh_fast(float x) {
    return 1.f - 2.f * __builtin_amdgcn_rcpf(1.f + __expf(2.f * x));
}

#define KEEPH(x) asm volatile("" : "+v"(x))
#define DECL16(P, R) \
  h2 P##0=pkh(R[0],R[1]),   P##1=pkh(R[2],R[3]),   P##2=pkh(R[4],R[5]),   P##3=pkh(R[6],R[7]),   \
     P##4=pkh(R[8],R[9]),   P##5=pkh(R[10],R[11]), P##6=pkh(R[12],R[13]), P##7=pkh(R[14],R[15]), \
     P##8=pkh(R[16],R[17]), P##9=pkh(R[18],R[19]), P##10=pkh(R[20],R[21]),P##11=pkh(R[22],R[23]),\
     P##12=pkh(R[24],R[25]),P##13=pkh(R[26],R[27]),P##14=pkh(R[28],R[29]),P##15=pkh(R[30],R[31]);
#define KEEP16(P) \
  KEEPH(P##0); KEEPH(P##1); KEEPH(P##2); KEEPH(P##3); KEEPH(P##4); KEEPH(P##5); \
  KEEPH(P##6); KEEPH(P##7); KEEPH(P##8); KEEPH(P##9); KEEPH(P##10); KEEPH(P##11); \
  KEEPH(P##12); KEEPH(P##13); KEEPH(P##14); KEEPH(P##15);

#define DOT4(j) { h2 s = bcast2(hx, j);      \
    aI = dot2(s, wi##j, aI);                 \
    aF = dot2(s, wf##j, aF);                 \
    aG = dot2(s, wg##j, aG);                 \
    aO = dot2(s, wo##j, aO); }

// ---------------------------------------------------------------------------
// fp32 -> fp16 convert (n multiple of 4)
// ---------------------------------------------------------------------------
__global__ __launch_bounds__(256) void cvt_f2h(
    const float* __restrict__ in, _Float16* __restrict__ out, int n)
{
    int base = (blockIdx.x * 256 + threadIdx.x) * 4;
    if (base < n) {
        float4 v = *(const float4*)(in + base);
        *(h2*)(out + base)     = pkh(v.x, v.y);
        *(h2*)(out + base + 2) = pkh(v.z, v.w);
    }
}

// ---------------------------------------------------------------------------
// MFMA GEMM: pre[M,512] = Ah[M,K] * Wh[512,K]^T + (b_ih + b_hh)
// 64x64 tile, 256 threads = 4 waves, each wave a 32x32 quadrant as 2x2
// mfma_f32_16x16x32_f16 subtiles. K-chunks of 32. LDS h2[64][20] (80B row
// stride: 16B-aligned, 2-way bank aliasing = free). Fragment layouts per
// verified m89/m120: A[m=lane&15][k=(lane>>4)*8+j], C/D row=(lane>>4)*4+reg,
// col=lane&15.
// ---------------------------------------------------------------------------
__global__ __launch_bounds__(256) void gemm_pre_mfma(
    const _Float16* __restrict__ A, int K, int rowStrideB, int t0, int tlog,
    const _Float16* __restrict__ W,
    const float* __restrict__ bi, const float* __restrict__ bh,
    float* __restrict__ C)
{
    __shared__ h2 As2[64][20];
    __shared__ h2 Bs2[64][20];
    const int tid  = threadIdx.x;
    const int row0 = blockIdx.x * 64;
    const int col0 = blockIdx.y * 64;
    const int w    = tid >> 6;
    const int lane = tid & 63;
    const int qm   = (w >> 1) * 32;
    const int qn   = (w & 1) * 32;
    const int fm   = lane & 15;
    const int fq   = lane >> 4;
    const int tmask = (1 << tlog) - 1;
    const int lrow = tid >> 2;          // staging row 0..63
    const int lk   = (tid & 3) * 8;     // staging k-offset (halfs)

    f32x4 acc00 = {0,0,0,0}, acc01 = {0,0,0,0};
    f32x4 acc10 = {0,0,0,0}, acc11 = {0,0,0,0};

    for (int k0 = 0; k0 < K; k0 += 32) {
        {
            int rg = row0 + lrow;
            int b_idx = rg >> tlog, tt = rg & tmask;
            const _Float16* ap = A + (size_t)b_idx * rowStrideB +
                                 (size_t)(t0 + tt) * K + (k0 + lk);
            *(float4*)&As2[lrow][(tid & 3) * 4] = *(const float4*)ap;
            const _Float16* wp = W + (size_t)(col0 + lrow) * K + (k0 + lk);
            *(float4*)&Bs2[lrow][(tid & 3) * 4] = *(const float4*)wp;
        }
        __syncthreads();
        half8 a0 = *(const half8*)&As2[qm + fm][fq * 4];
        half8 a1 = *(const half8*)&As2[qm + 16 + fm][fq * 4];
        half8 b0 = *(const half8*)&Bs2[qn + fm][fq * 4];
        half8 b1 = *(const half8*)&Bs2[qn + 16 + fm][fq * 4];
        acc00 = __builtin_amdgcn_mfma_f32_16x16x32_f16(a0, b0, acc00, 0, 0, 0);
        acc01 = __builtin_amdgcn_mfma_f32_16x16x32_f16(a0, b1, acc01, 0, 0, 0);
        acc10 = __builtin_amdgcn_mfma_f32_16x16x32_f16(a1, b0, acc10, 0, 0, 0);
        acc11 = __builtin_amdgcn_mfma_f32_16x16x32_f16(a1, b1, acc11, 0, 0, 0);
        __syncthreads();
    }

    const int g0 = col0 + qn + fm;
    const int g1 = g0 + 16;
    const float bb0 = bi[g0] + bh[g0];
    const float bb1 = bi[g1] + bh[g1];
    const int m0 = row0 + qm + fq * 4;
    #pragma unroll
    for (int r = 0; r < 4; r++) {
        C[(size_t)(m0 + r) * Gn + g0]      = acc00[r] + bb0;
        C[(size_t)(m0 + r) * Gn + g1]      = acc01[r] + bb1;
        C[(size_t)(m0 + 16 + r) * Gn + g0] = acc10[r] + bb0;
        C[(size_t)(m0 + 16 + r) * Gn + g1] = acc11[r] + bb1;
    }
}

// ---------------------------------------------------------------------------
// LSTM scan v5 (R9 structure), fp16-only trajectory store.
// 512 threads, one block per batch item. Thread (u = tid&127, kq = tid>>7):
// gates i,f,g,o of unit u over k in [32kq,32kq+32), 64 pinned half2 weights,
// v_dot2_f32_f16 (fp32 accumulate).
// ---------------------------------------------------------------------------
__global__ __launch_bounds__(512)
__attribute__((amdgpu_waves_per_eu(2, 2)))
void lstm_scan(
    const float* __restrict__ pre,     // [B*TCH, 512]
    const float* __restrict__ w_hh,    // [512, 128] (this layer)
    _Float16* __restrict__ hs16,       // [B, T, H] layer output (fp16)
    float* __restrict__ h_state, float* __restrict__ c_state,
    int t0, int TCH, int first)
{
    const int b    = blockIdx.x;
    const int tid  = threadIdx.x;
    const int lane = tid & 63;
    const int u    = tid & 127;        // hidden unit
    const int kq   = tid >> 7;         // k-quarter, wave-uniform

    __shared__ h2 h2_sh[Hn / 2];                 // h as 64 packed pairs
    __shared__ __align__(16) float4 psum[4][Hn]; // slots 1..3 used

    const float* rI = w_hh + (size_t)(0 * Hn + u) * Hn + kq * 32;
    const float* rF = w_hh + (size_t)(1 * Hn + u) * Hn + kq * 32;
    const float* rG = w_hh + (size_t)(2 * Hn + u) * Hn + kq * 32;
    const float* rO = w_hh + (size_t)(3 * Hn + u) * Hn + kq * 32;
    DECL16(wi, rI) DECL16(wf, rF) DECL16(wg, rG) DECL16(wo, rO)
    KEEP16(wi) KEEP16(wf) KEEP16(wg) KEEP16(wo)

    float cr = 0.f;
    if (tid < Hn && !first) cr = c_state[b * Hn + tid];
    if (tid < Hn / 2) {
        h2 hv = pkh(0.f, 0.f);
        if (!first) hv = pkh(h_state[b * Hn + 2 * tid],
                             h_state[b * Hn + 2 * tid + 1]);
        h2_sh[tid] = hv;
    }
    __syncthreads();

    const float* ppI = pre + (size_t)b * TCH * Gn + u;
    const float* ppF = ppI + Hn;
    const float* ppG = ppI + 2 * Hn;
    const float* ppO = ppI + 3 * Hn;
    _Float16* hsb16 = hs16 + ((size_t)b * Tn + t0) * Hn;

    float pI0 = 0.f, pF0 = 0.f, pG0 = 0.f, pO0 = 0.f;
    float pI1 = 0.f, pF1 = 0.f, pG1 = 0.f, pO1 = 0.f;
    if (kq == 3) {
        pI0 = ppI[0]; pF0 = ppF[0]; pG0 = ppG[0]; pO0 = ppO[0];
        if (TCH > 1) { pI1 = ppI[Gn]; pF1 = ppF[Gn]; pG1 = ppG[Gn]; pO1 = ppO[Gn]; }
        else         { pI1 = pI0; pF1 = pF0; pG1 = pG0; pO1 = pO0; }
    }

    const int hslot = kq * 16 + (lane & 15);

    float hlast = 0.f;
    for (int t = 0; t < TCH; t++) {
        h2 hx = h2_sh[hslot];

        float pvI = pI0, pvF = pF0, pvG = pG0, pvO = pO0;
        pI0 = pI1; pF0 = pF1; pG0 = pG1; pO0 = pO1;
        if (kq == 3) {
            int tn = (t + 2 < TCH) ? (t + 2) : (TCH - 1);
            size_t o = (size_t)tn * Gn;
            pI1 = ppI[o]; pF1 = ppF[o]; pG1 = ppG[o]; pO1 = ppO[o];
        }

        float aI = 0.f, aF = 0.f, aG = 0.f, aO = 0.f;
        DOT4(0)  DOT4(1)  DOT4(2)  DOT4(3)
        DOT4(4)  DOT4(5)  DOT4(6)  DOT4(7)
        DOT4(8)  DOT4(9)  DOT4(10) DOT4(11)
        DOT4(12) DOT4(13) DOT4(14) DOT4(15)

        if (kq == 3)
            psum[3][u] = make_float4(aI + pvI, aF + pvF, aG + pvG, aO + pvO);
        else if (kq != 0)
            psum[kq][u] = make_float4(aI, aF, aG, aO);
        BAR_LDS();

        if (tid < Hn) {                 // kq==0: reduce + update
            float4 s1 = psum[1][u], s2 = psum[2][u], s3 = psum[3][u];
            float gi = (aI + s1.x) + (s2.x + s3.x);
            float gf = (aF + s1.y) + (s2.y + s3.y);
            float gg = (aG + s1.z) + (s2.z + s3.z);
            float go = (aO + s1.w) + (s2.w + s3.w);
            float iv = sigm(gi);
            float fv = sigm(gf);
            float gv = tanh_fast(gg);
            float ov = sigm(go);
            cr = fv * cr + iv * gv;
            float hnew = ov * tanh_fast(cr);
            hlast = hnew;
            _Float16 hh = (_Float16)hnew;
            ((_Float16*)h2_sh)[u] = hh;               // b16 LDS write
            hsb16[(size_t)t * Hn + u] = hh;           // fp16 trajectory only
        }
        BAR_LDS();
    }

    if (tid < Hn) {
        h_state[b * Hn + u] = hlast;
        c_state[b * Hn + u] = cr;
    }
}

// ---------------------------------------------------------------------------
// Attention pooling + MLP head (reads fp16 hs). One block per batch item.
// ---------------------------------------------------------------------------
__global__ __launch_bounds__(256) void head_kernel(
    const _Float16* __restrict__ hs16,
    const float* __restrict__ w_attn, const float* __restrict__ b_attn,
    const float* __restrict__ w1, const float* __restrict__ b1,
    const float* __restrict__ w2, const float* __restrict__ b2,
    float* __restrict__ out)
{
    const int b = blockIdx.x;
    const int tid = threadIdx.x;
    __shared__ h2 wa2[Hn / 2];
    __shared__ __align__(16) float sc[Tn];
    __shared__ __align__(16) float red[256];
    __shared__ __align__(16) float ctx_sh[Hn];
    __shared__ __align__(16) float h1_sh[64];

    if (tid < Hn / 2) wa2[tid] = pkh(w_attn[2 * tid], w_attn[2 * tid + 1]);
    __syncthreads();

    const _Float16* hb = hs16 + (size_t)b * Tn * Hn;

    for (int t = tid; t < Tn; t += 256) {
        const h2* hp = (const h2*)(hb + (size_t)t * Hn);
        float s = 0.f;
        #pragma unroll
        for (int k = 0; k < 64; k++) s = dot2(hp[k], wa2[k], s);
        sc[t] = s + b_attn[0];
    }
    __syncthreads();

    float m = fmaxf(sc[tid], sc[tid + 256]);
    red[tid] = m; __syncthreads();
    for (int s_ = 128; s_ > 0; s_ >>= 1) {
        if (tid < s_) red[tid] = fmaxf(red[tid], red[tid + s_]);
        __syncthreads();
    }
    float mx = red[0];
    __syncthreads();
    float e0 = __expf(sc[tid] - mx), e1 = __expf(sc[tid + 256] - mx);
    sc[tid] = e0; sc[tid + 256] = e1;
    red[tid] = e0 + e1; __syncthreads();
    for (int s_ = 128; s_ > 0; s_ >>= 1) {
        if (tid < s_) red[tid] += red[tid + s_];
        __syncthreads();
    }
    float inv = 1.f / red[0];
    __syncthreads();

    {
        int jj = tid & 127, half = tid >> 7;
        float a = 0.f;
        for (int t = half * 256; t < half * 256 + 256; t++)
            a += sc[t] * (float)hb[(size_t)t * Hn + jj];
        red[tid] = a;
        __syncthreads();
        if (tid < Hn) ctx_sh[tid] = (red[tid] + red[tid + Hn]) * inv;
        __syncthreads();
    }

    if (tid < 64) {
        const float4* wvv = (const float4*)(w1 + (size_t)tid * Hn);
        const float4* cv = (const float4*)ctx_sh;
        float s = 0.f;
        #pragma unroll
        for (int k = 0; k < 32; k++) {
            float4 a = wvv[k], c = cv[k];
            s += a.x * c.x + a.y * c.y + a.z * c.z + a.w * c.w;
        }
        h1_sh[tid] = fmaxf(s + b1[tid], 0.f);
    }
    __syncthreads();

    if (tid < 4) {
        float s = 0.f;
        const float* wvv = w2 + tid * 64;
        #pragma unroll
        for (int k = 0; k < 64; k++) s += wvv[k] * h1_sh[k];
        out[b * 4 + tid] = s + b2[tid];
    }
}

// ---------------------------------------------------------------------------
extern "C" void kernel_launch(void* const* d_in, const int* in_sizes, int n_in,
                              void* d_out, int out_size, void* d_ws, size_t ws_size,
                              hipStream_t stream)
{
    const float* x        = (const float*)d_in[0];
    const float* w_ih0    = (const float*)d_in[1];
    const float* w_ih_rest= (const float*)d_in[2];
    const float* w_hh     = (const float*)d_in[3];
    const float* b_ih     = (const float*)d_in[4];
    const float* b_hh     = (const float*)d_in[5];
    const float* w_attn   = (const float*)d_in[6];
    const float* b_attn   = (const float*)d_in[7];
    const float* w1       = (const float*)d_in[8];
    const float* b1       = (const float*)d_in[9];
    const float* w2       = (const float*)d_in[10];
    const float* b2       = (const float*)d_in[11];
    float* out = (float*)d_out;

    const size_t nX  = (size_t)Bn * Tn * Dn;       // 2,097,152
    const size_t nHS = (size_t)Bn * Tn * Hn;       // 8,388,608
    const size_t nW0 = (size_t)Gn * Dn;            // 16,384
    const size_t nWR = (size_t)(Ln - 1) * Gn * Hn; // 131,072

    float* ws   = (float*)d_ws;
    float* h_st = ws;
    float* c_st = h_st + (size_t)Bn * Hn;
    float* pre  = c_st + (size_t)Bn * Hn;

    const size_t halfBytes = (nX + nHS + nW0 + nWR) * sizeof(_Float16);
    // Defensive: back off pre-chunk length down to 16 if workspace is small.
    // (Previous floor of 64 could exit the loop without fitting -> OOB writes.)
    int tch = 512;
    while (tch > 16) {
        size_t need = (2 * (size_t)Bn * Hn +
                       (size_t)Bn * tch * Gn) * sizeof(float) + halfBytes;
        if (need <= ws_size) break;
        tch >>= 1;
    }
    int tlog = 31 - __builtin_clz((unsigned)tch);

    _Float16* xh   = (_Float16*)(pre + (size_t)Bn * tch * Gn);
    _Float16* hs16 = xh + nX;
    _Float16* w0h  = hs16 + nHS;
    _Float16* wrh  = w0h + nW0;

    cvt_f2h<<<(int)((nX / 4 + 255) / 256), 256, 0, stream>>>(x, xh, (int)nX);
    cvt_f2h<<<(int)((nW0 / 4 + 255) / 256), 256, 0, stream>>>(w_ih0, w0h, (int)nW0);
    cvt_f2h<<<(int)((nWR / 4 + 255) / 256), 256, 0, stream>>>(w_ih_rest, wrh, (int)nWR);

    for (int l = 0; l < Ln; l++) {
        const _Float16* A = (l == 0) ? xh : hs16;
        int K = (l == 0) ? Dn : Hn;
        const _Float16* W = (l == 0) ? w0h : (wrh + (size_t)(l - 1) * Gn * Hn);
        const float* whl = w_hh + (size_t)l * Gn * Hn;
        for (int c = 0; c < Tn / tch; c++) {
            dim3 gg(Bn * tch / 64, 8);
            gemm_pre_mfma<<<gg, 256, 0, stream>>>(A, K, Tn * K, c * tch, tlog,
                                                  W, b_ih + l * Gn, b_hh + l * Gn, pre);
            lstm_scan<<<Bn, 512, 0, stream>>>(pre, whl, hs16, h_st, c_st,
                                              c * tch, tch, c == 0 ? 1 : 0);
        }
    }
    head_kernel<<<Bn, 256, 0, stream>>>(hs16, w_attn, b_attn, w1, b1, w2, b2, out);
}

// Round 2
// 1194.617 us; speedup vs baseline: 1.0562x; 1.0562x over previous
//
#include <hip/hip_runtime.h>
#include <math.h>

#define Bn 128
#define Tn 512
#define Dn 32
#define Hn 128
#define Gn 512   // 4*H
#define Ln 3

// LDS-only barrier: does NOT drain vmcnt.
#define BAR_LDS() asm volatile("s_waitcnt lgkmcnt(0)\n\ts_barrier" ::: "memory")

typedef _Float16 h2 __attribute__((ext_vector_type(2)));
typedef _Float16 half8 __attribute__((ext_vector_type(8)));   // MFMA A/B frag
typedef float f32x4 __attribute__((ext_vector_type(4)));      // MFMA acc

__device__ __forceinline__ float dot2(h2 a, h2 b, float c) {
    return __builtin_amdgcn_fdot2(a, b, c, false);
}
__device__ __forceinline__ h2 pkh(float a, float b) {
    h2 r; r.x = (_Float16)a; r.y = (_Float16)b; return r;
}
__device__ __forceinline__ float sigm(float x) {
    return __builtin_amdgcn_rcpf(1.f + __expf(-x));
}
__device__ __forceinline__ float tanh_fast(float x) {
    return 1.f - 2.f * __builtin_amdgcn_rcpf(1.f + __expf(2.f * x));
}

#define KEEPH(x) asm volatile("" : "+v"(x))
#define DECL16(P, R) \
  h2 P##0=pkh(R[0],R[1]),   P##1=pkh(R[2],R[3]),   P##2=pkh(R[4],R[5]),   P##3=pkh(R[6],R[7]),   \
     P##4=pkh(R[8],R[9]),   P##5=pkh(R[10],R[11]), P##6=pkh(R[12],R[13]), P##7=pkh(R[14],R[15]), \
     P##8=pkh(R[16],R[17]), P##9=pkh(R[18],R[19]), P##10=pkh(R[20],R[21]),P##11=pkh(R[22],R[23]),\
     P##12=pkh(R[24],R[25]),P##13=pkh(R[26],R[27]),P##14=pkh(R[28],R[29]),P##15=pkh(R[30],R[31]);
#define KEEP16(P) \
  KEEPH(P##0); KEEPH(P##1); KEEPH(P##2); KEEPH(P##3); KEEPH(P##4); KEEPH(P##5); \
  KEEPH(P##6); KEEPH(P##7); KEEPH(P##8); KEEPH(P##9); KEEPH(P##10); KEEPH(P##11); \
  KEEPH(P##12); KEEPH(P##13); KEEPH(P##14); KEEPH(P##15);

// dot-accumulate all 4 gates against a register h2 value
#define DOT4V(j) { \
    aI = dot2(hv##j, wi##j, aI);                 \
    aF = dot2(hv##j, wf##j, aF);                 \
    aG = dot2(hv##j, wg##j, aG);                 \
    aO = dot2(hv##j, wo##j, aO); }

// ---------------------------------------------------------------------------
// fp32 -> fp16 convert (n multiple of 4)
// ---------------------------------------------------------------------------
__global__ __launch_bounds__(256) void cvt_f2h(
    const float* __restrict__ in, _Float16* __restrict__ out, int n)
{
    int base = (blockIdx.x * 256 + threadIdx.x) * 4;
    if (base < n) {
        float4 v = *(const float4*)(in + base);
        *(h2*)(out + base)     = pkh(v.x, v.y);
        *(h2*)(out + base + 2) = pkh(v.z, v.w);
    }
}

// ---------------------------------------------------------------------------
// MFMA GEMM: pre[M,512] = Ah[M,K] * Wh[512,K]^T + (b_ih + b_hh)
// 64x64 tile, 256 threads = 4 waves, each wave a 32x32 quadrant as 2x2
// mfma_f32_16x16x32_f16 subtiles. K-chunks of 32. LDS h2[64][20] (80B row
// stride: 16B-aligned, 2-way bank aliasing = free).
// ---------------------------------------------------------------------------
__global__ __launch_bounds__(256) void gemm_pre_mfma(
    const _Float16* __restrict__ A, int K, int rowStrideB, int t0, int tlog,
    const _Float16* __restrict__ W,
    const float* __restrict__ bi, const float* __restrict__ bh,
    float* __restrict__ C)
{
    __shared__ h2 As2[64][20];
    __shared__ h2 Bs2[64][20];
    const int tid  = threadIdx.x;
    const int row0 = blockIdx.x * 64;
    const int col0 = blockIdx.y * 64;
    const int w    = tid >> 6;
    const int lane = tid & 63;
    const int qm   = (w >> 1) * 32;
    const int qn   = (w & 1) * 32;
    const int fm   = lane & 15;
    const int fq   = lane >> 4;
    const int tmask = (1 << tlog) - 1;
    const int lrow = tid >> 2;          // staging row 0..63
    const int lk   = (tid & 3) * 8;     // staging k-offset (halfs)

    f32x4 acc00 = {0,0,0,0}, acc01 = {0,0,0,0};
    f32x4 acc10 = {0,0,0,0}, acc11 = {0,0,0,0};

    for (int k0 = 0; k0 < K; k0 += 32) {
        {
            int rg = row0 + lrow;
            int b_idx = rg >> tlog, tt = rg & tmask;
            const _Float16* ap = A + (size_t)b_idx * rowStrideB +
                                 (size_t)(t0 + tt) * K + (k0 + lk);
            *(float4*)&As2[lrow][(tid & 3) * 4] = *(const float4*)ap;
            const _Float16* wp = W + (size_t)(col0 + lrow) * K + (k0 + lk);
            *(float4*)&Bs2[lrow][(tid & 3) * 4] = *(const float4*)wp;
        }
        __syncthreads();
        half8 a0 = *(const half8*)&As2[qm + fm][fq * 4];
        half8 a1 = *(const half8*)&As2[qm + 16 + fm][fq * 4];
        half8 b0 = *(const half8*)&Bs2[qn + fm][fq * 4];
        half8 b1 = *(const half8*)&Bs2[qn + 16 + fm][fq * 4];
        acc00 = __builtin_amdgcn_mfma_f32_16x16x32_f16(a0, b0, acc00, 0, 0, 0);
        acc01 = __builtin_amdgcn_mfma_f32_16x16x32_f16(a0, b1, acc01, 0, 0, 0);
        acc10 = __builtin_amdgcn_mfma_f32_16x16x32_f16(a1, b0, acc10, 0, 0, 0);
        acc11 = __builtin_amdgcn_mfma_f32_16x16x32_f16(a1, b1, acc11, 0, 0, 0);
        __syncthreads();
    }

    const int g0 = col0 + qn + fm;
    const int g1 = g0 + 16;
    const float bb0 = bi[g0] + bh[g0];
    const float bb1 = bi[g1] + bh[g1];
    const int m0 = row0 + qm + fq * 4;
    #pragma unroll
    for (int r = 0; r < 4; r++) {
        C[(size_t)(m0 + r) * Gn + g0]      = acc00[r] + bb0;
        C[(size_t)(m0 + r) * Gn + g1]      = acc01[r] + bb1;
        C[(size_t)(m0 + 16 + r) * Gn + g0] = acc10[r] + bb0;
        C[(size_t)(m0 + 16 + r) * Gn + g1] = acc11[r] + bb1;
    }
}

// ---------------------------------------------------------------------------
// LSTM scan v6: lane-adjacent k-split + in-register butterfly reduce.
// 512 threads, one block per batch item. Wave wv owns units wv*16..wv*16+15;
// within a 4-lane group, lane kq = lane&3 covers k in [32kq, 32kq+32) for all
// 4 gates of unit u = wv*16 + (lane>>2). Reduction across kq is a 2-level
// __shfl_xor butterfly (no LDS round-trip, no idle-wave tail); h is
// double-buffered in LDS so each timestep needs exactly ONE barrier.
// c-state is kept in registers, replicated across the 4 lanes of a group.
// ---------------------------------------------------------------------------
__global__ __launch_bounds__(512)
__attribute__((amdgpu_waves_per_eu(2, 2)))
void lstm_scan(
    const float* __restrict__ pre,     // [B*TCH, 512]
    const float* __restrict__ w_hh,    // [512, 128] (this layer)
    _Float16* __restrict__ hs16,       // [B, T, H] layer output (fp16)
    float* __restrict__ h_state, float* __restrict__ c_state,
    int t0, int TCH, int first)
{
    const int b    = blockIdx.x;
    const int tid  = threadIdx.x;
    const int lane = tid & 63;
    const int wv   = tid >> 6;
    const int kq   = lane & 3;             // k-quarter, lane-adjacent
    const int u    = wv * 16 + (lane >> 2);// hidden unit (128 unique)

    __shared__ h2 hbuf[2][Hn / 2];         // double-buffered h (fp16 pairs)

    const float* rI = w_hh + (size_t)(0 * Hn + u) * Hn + kq * 32;
    const float* rF = w_hh + (size_t)(1 * Hn + u) * Hn + kq * 32;
    const float* rG = w_hh + (size_t)(2 * Hn + u) * Hn + kq * 32;
    const float* rO = w_hh + (size_t)(3 * Hn + u) * Hn + kq * 32;
    DECL16(wi, rI) DECL16(wf, rF) DECL16(wg, rG) DECL16(wo, rO)
    KEEP16(wi) KEEP16(wf) KEEP16(wg) KEEP16(wo)

    // c replicated across the 4 lanes of each group
    float cr = first ? 0.f : c_state[b * Hn + u];
    if (tid < Hn / 2) {
        h2 hv = pkh(0.f, 0.f);
        if (!first) hv = pkh(h_state[b * Hn + 2 * tid],
                             h_state[b * Hn + 2 * tid + 1]);
        hbuf[0][tid] = hv;
    }
    __syncthreads();

    // per-lane pre pointer: gate kq of unit u
    const float* pp = pre + (size_t)b * TCH * Gn + kq * Hn + u;
    _Float16* hsb16 = hs16 + ((size_t)b * Tn + t0) * Hn;

    // prefetch pre 2 steps ahead
    float p0 = pp[0];
    float p1 = (TCH > 1) ? pp[Gn] : p0;

    // gate-select masks (which accumulator receives this lane's pre value)
    const float mI = (kq == 0) ? 1.f : 0.f;
    const float mF = (kq == 1) ? 1.f : 0.f;
    const float mG = (kq == 2) ? 1.f : 0.f;
    const float mO = (kq == 3) ? 1.f : 0.f;

    float hlast = 0.f;
    for (int t = 0; t < TCH; t++) {
        // read this lane's 32 h values (16 h2) for its k-quarter
        const h2* hrow = &hbuf[t & 1][kq * 16];
        half8 hAv = *(const half8*)(hrow);
        half8 hBv = *(const half8*)(hrow + 4);
        half8 hCv = *(const half8*)(hrow + 8);
        half8 hDv = *(const half8*)(hrow + 12);
        h2 hv0  = ((const h2*)&hAv)[0], hv1  = ((const h2*)&hAv)[1];
        h2 hv2  = ((const h2*)&hAv)[2], hv3  = ((const h2*)&hAv)[3];
        h2 hv4  = ((const h2*)&hBv)[0], hv5  = ((const h2*)&hBv)[1];
        h2 hv6  = ((const h2*)&hBv)[2], hv7  = ((const h2*)&hBv)[3];
        h2 hv8  = ((const h2*)&hCv)[0], hv9  = ((const h2*)&hCv)[1];
        h2 hv10 = ((const h2*)&hCv)[2], hv11 = ((const h2*)&hCv)[3];
        h2 hv12 = ((const h2*)&hDv)[0], hv13 = ((const h2*)&hDv)[1];
        h2 hv14 = ((const h2*)&hDv)[2], hv15 = ((const h2*)&hDv)[3];

        float pv = p0;
        p0 = p1;
        {
            int tn = (t + 2 < TCH) ? (t + 2) : (TCH - 1);
            p1 = pp[(size_t)tn * Gn];
        }

        float aI = 0.f, aF = 0.f, aG = 0.f, aO = 0.f;
        DOT4V(0)  DOT4V(1)  DOT4V(2)  DOT4V(3)
        DOT4V(4)  DOT4V(5)  DOT4V(6)  DOT4V(7)
        DOT4V(8)  DOT4V(9)  DOT4V(10) DOT4V(11)
        DOT4V(12) DOT4V(13) DOT4V(14) DOT4V(15)

        // fold this lane's pre value into its own gate accumulator
        aI = fmaf(pv, mI, aI);
        aF = fmaf(pv, mF, aF);
        aG = fmaf(pv, mG, aG);
        aO = fmaf(pv, mO, aO);

        // butterfly reduce across the 4 kq lanes (all lanes end with full sums)
        aI += __shfl_xor(aI, 1); aF += __shfl_xor(aF, 1);
        aG += __shfl_xor(aG, 1); aO += __shfl_xor(aO, 1);
        aI += __shfl_xor(aI, 2); aF += __shfl_xor(aF, 2);
        aG += __shfl_xor(aG, 2); aO += __shfl_xor(aO, 2);

        float iv = sigm(aI);
        float fv = sigm(aF);
        float gv = tanh_fast(aG);
        float ov = sigm(aO);
        cr = fv * cr + iv * gv;
        float hnew = ov * tanh_fast(cr);
        hlast = hnew;
        _Float16 hh = (_Float16)hnew;
        if (kq == 0) {
            ((_Float16*)hbuf[(t + 1) & 1])[u] = hh;   // next-step h buffer
            hsb16[(size_t)t * Hn + u] = hh;           // fp16 trajectory
        }
        BAR_LDS();
    }

    if (kq == 0) {
        h_state[b * Hn + u] = hlast;
        c_state[b * Hn + u] = cr;
    }
}

// ---------------------------------------------------------------------------
// Attention pooling + MLP head (reads fp16 hs). One block per batch item.
// ---------------------------------------------------------------------------
__global__ __launch_bounds__(256) void head_kernel(
    const _Float16* __restrict__ hs16,
    const float* __restrict__ w_attn, const float* __restrict__ b_attn,
    const float* __restrict__ w1, const float* __restrict__ b1,
    const float* __restrict__ w2, const float* __restrict__ b2,
    float* __restrict__ out)
{
    const int b = blockIdx.x;
    const int tid = threadIdx.x;
    __shared__ h2 wa2[Hn / 2];
    __shared__ __align__(16) float sc[Tn];
    __shared__ __align__(16) float red[256];
    __shared__ __align__(16) float ctx_sh[Hn];
    __shared__ __align__(16) float h1_sh[64];

    if (tid < Hn / 2) wa2[tid] = pkh(w_attn[2 * tid], w_attn[2 * tid + 1]);
    __syncthreads();

    const _Float16* hb = hs16 + (size_t)b * Tn * Hn;

    for (int t = tid; t < Tn; t += 256) {
        const h2* hp = (const h2*)(hb + (size_t)t * Hn);
        float s = 0.f;
        #pragma unroll
        for (int k = 0; k < 64; k++) s = dot2(hp[k], wa2[k], s);
        sc[t] = s + b_attn[0];
    }
    __syncthreads();

    float m = fmaxf(sc[tid], sc[tid + 256]);
    red[tid] = m; __syncthreads();
    for (int s_ = 128; s_ > 0; s_ >>= 1) {
        if (tid < s_) red[tid] = fmaxf(red[tid], red[tid + s_]);
        __syncthreads();
    }
    float mx = red[0];
    __syncthreads();
    float e0 = __expf(sc[tid] - mx), e1 = __expf(sc[tid + 256] - mx);
    sc[tid] = e0; sc[tid + 256] = e1;
    red[tid] = e0 + e1; __syncthreads();
    for (int s_ = 128; s_ > 0; s_ >>= 1) {
        if (tid < s_) red[tid] += red[tid + s_];
        __syncthreads();
    }
    float inv = 1.f / red[0];
    __syncthreads();

    {
        int jj = tid & 127, half = tid >> 7;
        float a = 0.f;
        for (int t = half * 256; t < half * 256 + 256; t++)
            a += sc[t] * (float)hb[(size_t)t * Hn + jj];
        red[tid] = a;
        __syncthreads();
        if (tid < Hn) ctx_sh[tid] = (red[tid] + red[tid + Hn]) * inv;
        __syncthreads();
    }

    if (tid < 64) {
        const float4* wvv = (const float4*)(w1 + (size_t)tid * Hn);
        const float4* cv = (const float4*)ctx_sh;
        float s = 0.f;
        #pragma unroll
        for (int k = 0; k < 32; k++) {
            float4 a = wvv[k], c = cv[k];
            s += a.x * c.x + a.y * c.y + a.z * c.z + a.w * c.w;
        }
        h1_sh[tid] = fmaxf(s + b1[tid], 0.f);
    }
    __syncthreads();

    if (tid < 4) {
        float s = 0.f;
        const float* wvv = w2 + tid * 64;
        #pragma unroll
        for (int k = 0; k < 64; k++) s += wvv[k] * h1_sh[k];
        out[b * 4 + tid] = s + b2[tid];
    }
}

// ---------------------------------------------------------------------------
extern "C" void kernel_launch(void* const* d_in, const int* in_sizes, int n_in,
                              void* d_out, int out_size, void* d_ws, size_t ws_size,
                              hipStream_t stream)
{
    const float* x        = (const float*)d_in[0];
    const float* w_ih0    = (const float*)d_in[1];
    const float* w_ih_rest= (const float*)d_in[2];
    const float* w_hh     = (const float*)d_in[3];
    const float* b_ih     = (const float*)d_in[4];
    const float* b_hh     = (const float*)d_in[5];
    const float* w_attn   = (const float*)d_in[6];
    const float* b_attn   = (const float*)d_in[7];
    const float* w1       = (const float*)d_in[8];
    const float* b1       = (const float*)d_in[9];
    const float* w2       = (const float*)d_in[10];
    const float* b2       = (const float*)d_in[11];
    float* out = (float*)d_out;

    const size_t nX  = (size_t)Bn * Tn * Dn;       // 2,097,152
    const size_t nHS = (size_t)Bn * Tn * Hn;       // 8,388,608
    const size_t nW0 = (size_t)Gn * Dn;            // 16,384
    const size_t nWR = (size_t)(Ln - 1) * Gn * Hn; // 131,072

    float* ws   = (float*)d_ws;
    float* h_st = ws;
    float* c_st = h_st + (size_t)Bn * Hn;
    float* pre  = c_st + (size_t)Bn * Hn;

    const size_t halfBytes = (nX + nHS + nW0 + nWR) * sizeof(_Float16);
    int tch = 512;
    while (tch > 16) {
        size_t need = (2 * (size_t)Bn * Hn +
                       (size_t)Bn * tch * Gn) * sizeof(float) + halfBytes;
        if (need <= ws_size) break;
        tch >>= 1;
    }
    int tlog = 31 - __builtin_clz((unsigned)tch);

    _Float16* xh   = (_Float16*)(pre + (size_t)Bn * tch * Gn);
    _Float16* hs16 = xh + nX;
    _Float16* w0h  = hs16 + nHS;
    _Float16* wrh  = w0h + nW0;

    cvt_f2h<<<(int)((nX / 4 + 255) / 256), 256, 0, stream>>>(x, xh, (int)nX);
    cvt_f2h<<<(int)((nW0 / 4 + 255) / 256), 256, 0, stream>>>(w_ih0, w0h, (int)nW0);
    cvt_f2h<<<(int)((nWR / 4 + 255) / 256), 256, 0, stream>>>(w_ih_rest, wrh, (int)nWR);

    for (int l = 0; l < Ln; l++) {
        const _Float16* A = (l == 0) ? xh : hs16;
        int K = (l == 0) ? Dn : Hn;
        const _Float16* W = (l == 0) ? w0h : (wrh + (size_t)(l - 1) * Gn * Hn);
        const float* whl = w_hh + (size_t)l * Gn * Hn;
        for (int c = 0; c < Tn / tch; c++) {
            dim3 gg(Bn * tch / 64, 8);
            gemm_pre_mfma<<<gg, 256, 0, stream>>>(A, K, Tn * K, c * tch, tlog,
                                                  W, b_ih + l * Gn, b_hh + l * Gn, pre);
            lstm_scan<<<Bn, 512, 0, stream>>>(pre, whl, hs16, h_st, c_st,
                                              c * tch, tch, c == 0 ? 1 : 0);
        }
    }
    head_kernel<<<Bn, 256, 0, stream>>>(hs16, w_attn, b_attn, w1, b1, w2, b2, out);
}

// Round 3
// 1071.091 us; speedup vs baseline: 1.1780x; 1.1153x over previous
//
#include <hip/hip_runtime.h>
#include <math.h>

#define Bn 128
#define Tn 512
#define Dn 32
#define Hn 128
#define Gn 512   // 4*H
#define Ln 3

// LDS-only barrier: does NOT drain vmcnt.
#define BAR_LDS() asm volatile("s_waitcnt lgkmcnt(0)\n\ts_barrier" ::: "memory")

typedef _Float16 h2 __attribute__((ext_vector_type(2)));
typedef _Float16 half8 __attribute__((ext_vector_type(8)));   // MFMA A/B frag
typedef float f32x4 __attribute__((ext_vector_type(4)));      // MFMA acc

__device__ __forceinline__ float dot2(h2 a, h2 b, float c) {
    return __builtin_amdgcn_fdot2(a, b, c, false);
}
__device__ __forceinline__ h2 pkh(float a, float b) {
    h2 r; r.x = (_Float16)a; r.y = (_Float16)b; return r;
}
__device__ __forceinline__ float sigm(float x) {
    return __builtin_amdgcn_rcpf(1.f + __expf(-x));
}
__device__ __forceinline__ float tanh_fast(float x) {
    return 1.f - 2.f * __builtin_amdgcn_rcpf(1.f + __expf(2.f * x));
}

// quad-local butterfly add via DPP (no DS pipe, ~4cyc dep latency).
// xor1 = quad_perm(1,0,3,2) = 0xB1 ; xor2 = quad_perm(2,3,0,1) = 0x4E
#define DPPADD(a, CTRL) { \
    int _t = __builtin_amdgcn_update_dpp(0, __builtin_bit_cast(int, a), \
                                         CTRL, 0xF, 0xF, true); \
    a += __builtin_bit_cast(float, _t); }

#define KEEPH(x) asm volatile("" : "+v"(x))
#define DECL16(P, R) \
  h2 P##0=pkh(R[0],R[1]),   P##1=pkh(R[2],R[3]),   P##2=pkh(R[4],R[5]),   P##3=pkh(R[6],R[7]),   \
     P##4=pkh(R[8],R[9]),   P##5=pkh(R[10],R[11]), P##6=pkh(R[12],R[13]), P##7=pkh(R[14],R[15]), \
     P##8=pkh(R[16],R[17]), P##9=pkh(R[18],R[19]), P##10=pkh(R[20],R[21]),P##11=pkh(R[22],R[23]),\
     P##12=pkh(R[24],R[25]),P##13=pkh(R[26],R[27]),P##14=pkh(R[28],R[29]),P##15=pkh(R[30],R[31]);
#define KEEP16(P) \
  KEEPH(P##0); KEEPH(P##1); KEEPH(P##2); KEEPH(P##3); KEEPH(P##4); KEEPH(P##5); \
  KEEPH(P##6); KEEPH(P##7); KEEPH(P##8); KEEPH(P##9); KEEPH(P##10); KEEPH(P##11); \
  KEEPH(P##12); KEEPH(P##13); KEEPH(P##14); KEEPH(P##15);

// dot-accumulate all 4 gates against a register h2 value
#define DOT4V(j) { \
    aI = dot2(hv##j, wi##j, aI);                 \
    aF = dot2(hv##j, wf##j, aF);                 \
    aG = dot2(hv##j, wg##j, aG);                 \
    aO = dot2(hv##j, wo##j, aO); }

// ---------------------------------------------------------------------------
// fp32 -> fp16 convert (n multiple of 4)
// ---------------------------------------------------------------------------
__global__ __launch_bounds__(256) void cvt_f2h(
    const float* __restrict__ in, _Float16* __restrict__ out, int n)
{
    int base = (blockIdx.x * 256 + threadIdx.x) * 4;
    if (base < n) {
        float4 v = *(const float4*)(in + base);
        *(h2*)(out + base)     = pkh(v.x, v.y);
        *(h2*)(out + base + 2) = pkh(v.z, v.w);
    }
}

// ---------------------------------------------------------------------------
// MFMA GEMM: pre[M,512] = Ah[M,K] * Wh[512,K]^T + (b_ih + b_hh)
// 64x64 tile, 256 threads = 4 waves, each wave a 32x32 quadrant as 2x2
// mfma_f32_16x16x32_f16 subtiles. K-chunks of 32. LDS h2[64][20] (80B row
// stride: 16B-aligned, 2-way bank aliasing = free).
// ---------------------------------------------------------------------------
__global__ __launch_bounds__(256) void gemm_pre_mfma(
    const _Float16* __restrict__ A, int K, int rowStrideB, int t0, int tlog,
    const _Float16* __restrict__ W,
    const float* __restrict__ bi, const float* __restrict__ bh,
    float* __restrict__ C)
{
    __shared__ h2 As2[64][20];
    __shared__ h2 Bs2[64][20];
    const int tid  = threadIdx.x;
    const int row0 = blockIdx.x * 64;
    const int col0 = blockIdx.y * 64;
    const int w    = tid >> 6;
    const int lane = tid & 63;
    const int qm   = (w >> 1) * 32;
    const int qn   = (w & 1) * 32;
    const int fm   = lane & 15;
    const int fq   = lane >> 4;
    const int tmask = (1 << tlog) - 1;
    const int lrow = tid >> 2;          // staging row 0..63
    const int lk   = (tid & 3) * 8;     // staging k-offset (halfs)

    f32x4 acc00 = {0,0,0,0}, acc01 = {0,0,0,0};
    f32x4 acc10 = {0,0,0,0}, acc11 = {0,0,0,0};

    for (int k0 = 0; k0 < K; k0 += 32) {
        {
            int rg = row0 + lrow;
            int b_idx = rg >> tlog, tt = rg & tmask;
            const _Float16* ap = A + (size_t)b_idx * rowStrideB +
                                 (size_t)(t0 + tt) * K + (k0 + lk);
            *(float4*)&As2[lrow][(tid & 3) * 4] = *(const float4*)ap;
            const _Float16* wp = W + (size_t)(col0 + lrow) * K + (k0 + lk);
            *(float4*)&Bs2[lrow][(tid & 3) * 4] = *(const float4*)wp;
        }
        __syncthreads();
        half8 a0 = *(const half8*)&As2[qm + fm][fq * 4];
        half8 a1 = *(const half8*)&As2[qm + 16 + fm][fq * 4];
        half8 b0 = *(const half8*)&Bs2[qn + fm][fq * 4];
        half8 b1 = *(const half8*)&Bs2[qn + 16 + fm][fq * 4];
        acc00 = __builtin_amdgcn_mfma_f32_16x16x32_f16(a0, b0, acc00, 0, 0, 0);
        acc01 = __builtin_amdgcn_mfma_f32_16x16x32_f16(a0, b1, acc01, 0, 0, 0);
        acc10 = __builtin_amdgcn_mfma_f32_16x16x32_f16(a1, b0, acc10, 0, 0, 0);
        acc11 = __builtin_amdgcn_mfma_f32_16x16x32_f16(a1, b1, acc11, 0, 0, 0);
        __syncthreads();
    }

    const int g0 = col0 + qn + fm;
    const int g1 = g0 + 16;
    const float bb0 = bi[g0] + bh[g0];
    const float bb1 = bi[g1] + bh[g1];
    const int m0 = row0 + qm + fq * 4;
    #pragma unroll
    for (int r = 0; r < 4; r++) {
        C[(size_t)(m0 + r) * Gn + g0]      = acc00[r] + bb0;
        C[(size_t)(m0 + r) * Gn + g1]      = acc01[r] + bb1;
        C[(size_t)(m0 + 16 + r) * Gn + g0] = acc10[r] + bb0;
        C[(size_t)(m0 + 16 + r) * Gn + g1] = acc11[r] + bb1;
    }
}

// ---------------------------------------------------------------------------
// LSTM scan v7: lane-adjacent k-split + DPP quad_perm butterfly reduce.
// 512 threads, one block per batch item. Wave wv owns units wv*16..wv*16+15;
// within a 4-lane quad, lane kq = lane&3 covers k in [32kq, 32kq+32) for all
// 4 gates of unit u = wv*16 + (lane>>2). Cross-kq reduce = 2-level quad_perm
// DPP add (pure VALU, no DS traffic). h double-buffered in LDS; ONE barrier
// per timestep. c replicated in registers across the quad. pre prefetched 2
// steps ahead with an incrementing pointer (main loop) + 2-step epilogue.
// ---------------------------------------------------------------------------
__global__ __launch_bounds__(512)
__attribute__((amdgpu_waves_per_eu(2, 2)))
void lstm_scan(
    const float* __restrict__ pre,     // [B*TCH, 512]
    const float* __restrict__ w_hh,    // [512, 128] (this layer)
    _Float16* __restrict__ hs16,       // [B, T, H] layer output (fp16)
    float* __restrict__ h_state, float* __restrict__ c_state,
    int t0, int TCH, int first)
{
    const int b    = blockIdx.x;
    const int tid  = threadIdx.x;
    const int lane = tid & 63;
    const int wv   = tid >> 6;
    const int kq   = lane & 3;             // k-quarter, quad-adjacent
    const int u    = wv * 16 + (lane >> 2);// hidden unit (128 unique)

    __shared__ h2 hbuf[2][Hn / 2];         // double-buffered h (fp16 pairs)

    const float* rI = w_hh + (size_t)(0 * Hn + u) * Hn + kq * 32;
    const float* rF = w_hh + (size_t)(1 * Hn + u) * Hn + kq * 32;
    const float* rG = w_hh + (size_t)(2 * Hn + u) * Hn + kq * 32;
    const float* rO = w_hh + (size_t)(3 * Hn + u) * Hn + kq * 32;
    DECL16(wi, rI) DECL16(wf, rF) DECL16(wg, rG) DECL16(wo, rO)
    KEEP16(wi) KEEP16(wf) KEEP16(wg) KEEP16(wo)

    // c replicated across the 4 lanes of each quad
    float cr = first ? 0.f : c_state[b * Hn + u];
    if (tid < Hn / 2) {
        h2 hv = pkh(0.f, 0.f);
        if (!first) hv = pkh(h_state[b * Hn + 2 * tid],
                             h_state[b * Hn + 2 * tid + 1]);
        hbuf[0][tid] = hv;
    }
    __syncthreads();

    // per-lane pre pointer: gate kq of unit u
    const float* pp = pre + (size_t)b * TCH * Gn + kq * Hn + u;
    _Float16* hswr = hs16 + ((size_t)b * Tn + t0) * Hn + u;  // kq==0 lanes

    // gate-select masks (which accumulator receives this lane's pre value)
    const float mI = (kq == 0) ? 1.f : 0.f;
    const float mF = (kq == 1) ? 1.f : 0.f;
    const float mG = (kq == 2) ? 1.f : 0.f;
    const float mO = (kq == 3) ? 1.f : 0.f;

    float hlast = 0.f;

    // one timestep body; pv = this step's pre value for this lane's gate
    auto body = [&](int t, float pv) {
        const h2* hrow = &hbuf[t & 1][kq * 16];
        half8 hAv = *(const half8*)(hrow);
        half8 hBv = *(const half8*)(hrow + 4);
        half8 hCv = *(const half8*)(hrow + 8);
        half8 hDv = *(const half8*)(hrow + 12);
        h2 hv0  = ((const h2*)&hAv)[0], hv1  = ((const h2*)&hAv)[1];
        h2 hv2  = ((const h2*)&hAv)[2], hv3  = ((const h2*)&hAv)[3];
        h2 hv4  = ((const h2*)&hBv)[0], hv5  = ((const h2*)&hBv)[1];
        h2 hv6  = ((const h2*)&hBv)[2], hv7  = ((const h2*)&hBv)[3];
        h2 hv8  = ((const h2*)&hCv)[0], hv9  = ((const h2*)&hCv)[1];
        h2 hv10 = ((const h2*)&hCv)[2], hv11 = ((const h2*)&hCv)[3];
        h2 hv12 = ((const h2*)&hDv)[0], hv13 = ((const h2*)&hDv)[1];
        h2 hv14 = ((const h2*)&hDv)[2], hv15 = ((const h2*)&hDv)[3];

        float aI = 0.f, aF = 0.f, aG = 0.f, aO = 0.f;
        DOT4V(0)  DOT4V(1)  DOT4V(2)  DOT4V(3)
        DOT4V(4)  DOT4V(5)  DOT4V(6)  DOT4V(7)
        DOT4V(8)  DOT4V(9)  DOT4V(10) DOT4V(11)
        DOT4V(12) DOT4V(13) DOT4V(14) DOT4V(15)

        // fold this lane's pre value into its own gate accumulator
        aI = fmaf(pv, mI, aI);
        aF = fmaf(pv, mF, aF);
        aG = fmaf(pv, mG, aG);
        aO = fmaf(pv, mO, aO);

        // quad butterfly via DPP (all 4 lanes end with full sums)
        DPPADD(aI, 0xB1) DPPADD(aF, 0xB1) DPPADD(aG, 0xB1) DPPADD(aO, 0xB1)
        DPPADD(aI, 0x4E) DPPADD(aF, 0x4E) DPPADD(aG, 0x4E) DPPADD(aO, 0x4E)

        float iv = sigm(aI);
        float fv = sigm(aF);
        float gv = tanh_fast(aG);
        float ov = sigm(aO);
        cr = fv * cr + iv * gv;
        float hnew = ov * tanh_fast(cr);
        hlast = hnew;
        _Float16 hh = (_Float16)hnew;
        if (kq == 0) {
            ((_Float16*)hbuf[(t + 1) & 1])[u] = hh;   // next-step h buffer
            *hswr = hh;                               // fp16 trajectory
        }
        hswr += Hn;
        BAR_LDS();
    };

    // prefetch pre 2 steps ahead with an incrementing pointer
    float p0 = pp[0];
    float p1 = (TCH > 1) ? pp[Gn] : p0;
    const float* pld = pp + 2 * (size_t)Gn;

    const int TCH2 = TCH - 2;
    for (int t = 0; t < TCH2; t++) {
        float pv = p0; p0 = p1;
        p1 = *pld; pld += Gn;
        body(t, pv);
    }
    { float pv = p0; p0 = p1; body(TCH2, pv); }
    body(TCH2 + 1, p0);

    if (kq == 0) {
        h_state[b * Hn + u] = hlast;
        c_state[b * Hn + u] = cr;
    }
}

// ---------------------------------------------------------------------------
// Attention pooling + MLP head (reads fp16 hs). One block per batch item.
// ---------------------------------------------------------------------------
__global__ __launch_bounds__(256) void head_kernel(
    const _Float16* __restrict__ hs16,
    const float* __restrict__ w_attn, const float* __restrict__ b_attn,
    const float* __restrict__ w1, const float* __restrict__ b1,
    const float* __restrict__ w2, const float* __restrict__ b2,
    float* __restrict__ out)
{
    const int b = blockIdx.x;
    const int tid = threadIdx.x;
    __shared__ h2 wa2[Hn / 2];
    __shared__ __align__(16) float sc[Tn];
    __shared__ __align__(16) float red[256];
    __shared__ __align__(16) float ctx_sh[Hn];
    __shared__ __align__(16) float h1_sh[64];

    if (tid < Hn / 2) wa2[tid] = pkh(w_attn[2 * tid], w_attn[2 * tid + 1]);
    __syncthreads();

    const _Float16* hb = hs16 + (size_t)b * Tn * Hn;

    for (int t = tid; t < Tn; t += 256) {
        const h2* hp = (const h2*)(hb + (size_t)t * Hn);
        float s = 0.f;
        #pragma unroll
        for (int k = 0; k < 64; k++) s = dot2(hp[k], wa2[k], s);
        sc[t] = s + b_attn[0];
    }
    __syncthreads();

    float m = fmaxf(sc[tid], sc[tid + 256]);
    red[tid] = m; __syncthreads();
    for (int s_ = 128; s_ > 0; s_ >>= 1) {
        if (tid < s_) red[tid] = fmaxf(red[tid], red[tid + s_]);
        __syncthreads();
    }
    float mx = red[0];
    __syncthreads();
    float e0 = __expf(sc[tid] - mx), e1 = __expf(sc[tid + 256] - mx);
    sc[tid] = e0; sc[tid + 256] = e1;
    red[tid] = e0 + e1; __syncthreads();
    for (int s_ = 128; s_ > 0; s_ >>= 1) {
        if (tid < s_) red[tid] += red[tid + s_];
        __syncthreads();
    }
    float inv = 1.f / red[0];
    __syncthreads();

    {
        int jj = tid & 127, half = tid >> 7;
        float a = 0.f;
        for (int t = half * 256; t < half * 256 + 256; t++)
            a += sc[t] * (float)hb[(size_t)t * Hn + jj];
        red[tid] = a;
        __syncthreads();
        if (tid < Hn) ctx_sh[tid] = (red[tid] + red[tid + Hn]) * inv;
        __syncthreads();
    }

    if (tid < 64) {
        const float4* wvv = (const float4*)(w1 + (size_t)tid * Hn);
        const float4* cv = (const float4*)ctx_sh;
        float s = 0.f;
        #pragma unroll
        for (int k = 0; k < 32; k++) {
            float4 a = wvv[k], c = cv[k];
            s += a.x * c.x + a.y * c.y + a.z * c.z + a.w * c.w;
        }
        h1_sh[tid] = fmaxf(s + b1[tid], 0.f);
    }
    __syncthreads();

    if (tid < 4) {
        float s = 0.f;
        const float* wvv = w2 + tid * 64;
        #pragma unroll
        for (int k = 0; k < 64; k++) s += wvv[k] * h1_sh[k];
        out[b * 4 + tid] = s + b2[tid];
    }
}

// ---------------------------------------------------------------------------
extern "C" void kernel_launch(void* const* d_in, const int* in_sizes, int n_in,
                              void* d_out, int out_size, void* d_ws, size_t ws_size,
                              hipStream_t stream)
{
    const float* x        = (const float*)d_in[0];
    const float* w_ih0    = (const float*)d_in[1];
    const float* w_ih_rest= (const float*)d_in[2];
    const float* w_hh     = (const float*)d_in[3];
    const float* b_ih     = (const float*)d_in[4];
    const float* b_hh     = (const float*)d_in[5];
    const float* w_attn   = (const float*)d_in[6];
    const float* b_attn   = (const float*)d_in[7];
    const float* w1       = (const float*)d_in[8];
    const float* b1       = (const float*)d_in[9];
    const float* w2       = (const float*)d_in[10];
    const float* b2       = (const float*)d_in[11];
    float* out = (float*)d_out;

    const size_t nX  = (size_t)Bn * Tn * Dn;       // 2,097,152
    const size_t nHS = (size_t)Bn * Tn * Hn;       // 8,388,608
    const size_t nW0 = (size_t)Gn * Dn;            // 16,384
    const size_t nWR = (size_t)(Ln - 1) * Gn * Hn; // 131,072

    float* ws   = (float*)d_ws;
    float* h_st = ws;
    float* c_st = h_st + (size_t)Bn * Hn;
    float* pre  = c_st + (size_t)Bn * Hn;

    const size_t halfBytes = (nX + nHS + nW0 + nWR) * sizeof(_Float16);
    int tch = 512;
    while (tch > 16) {
        size_t need = (2 * (size_t)Bn * Hn +
                       (size_t)Bn * tch * Gn) * sizeof(float) + halfBytes;
        if (need <= ws_size) break;
        tch >>= 1;
    }
    int tlog = 31 - __builtin_clz((unsigned)tch);

    _Float16* xh   = (_Float16*)(pre + (size_t)Bn * tch * Gn);
    _Float16* hs16 = xh + nX;
    _Float16* w0h  = hs16 + nHS;
    _Float16* wrh  = w0h + nW0;

    cvt_f2h<<<(int)((nX / 4 + 255) / 256), 256, 0, stream>>>(x, xh, (int)nX);
    cvt_f2h<<<(int)((nW0 / 4 + 255) / 256), 256, 0, stream>>>(w_ih0, w0h, (int)nW0);
    cvt_f2h<<<(int)((nWR / 4 + 255) / 256), 256, 0, stream>>>(w_ih_rest, wrh, (int)nWR);

    for (int l = 0; l < Ln; l++) {
        const _Float16* A = (l == 0) ? xh : hs16;
        int K = (l == 0) ? Dn : Hn;
        const _Float16* W = (l == 0) ? w0h : (wrh + (size_t)(l - 1) * Gn * Hn);
        const float* whl = w_hh + (size_t)l * Gn * Hn;
        for (int c = 0; c < Tn / tch; c++) {
            dim3 gg(Bn * tch / 64, 8);
            gemm_pre_mfma<<<gg, 256, 0, stream>>>(A, K, Tn * K, c * tch, tlog,
                                                  W, b_ih + l * Gn, b_hh + l * Gn, pre);
            lstm_scan<<<Bn, 512, 0, stream>>>(pre, whl, hs16, h_st, c_st,
                                              c * tch, tch, c == 0 ? 1 : 0);
        }
    }
    head_kernel<<<Bn, 256, 0, stream>>>(hs16, w_attn, b_attn, w1, b1, w2, b2, out);
}